// Round 10
// baseline (12006.057 us; speedup 1.0000x reference)
//
#include <hip/hip_runtime.h>
#include <hip/hip_bf16.h>

typedef __bf16 bf16x8 __attribute__((ext_vector_type(8)));
typedef float  f32x4  __attribute__((ext_vector_type(4)));

#define MFMA16(a, b, c) __builtin_amdgcn_mfma_f32_16x16x32_bf16((a), (b), (c), 0, 0, 0)

namespace {
constexpr int T_   = 80;
constexpr int B_   = 4096;
constexpr int H_   = 256;
constexpr int HP_  = 264;   // padded LDS row stride
constexpr int V_   = 80;
constexpr int ROWS = 32;    // batch rows per block; 128 blocks
constexpr int OUT_HN = B_ * V_;              // fp32 element offsets in d_out
constexpr int OUT_CN = OUT_HN + 2 * B_ * H_;
// hi plane at [0, WS_PLANE), lo plane at [WS_PLANE, 2*WS_PLANE) in d_ws
constexpr int WS_WHH0 = 0;
constexpr int WS_WIH1 = 262144;
constexpr int WS_WHH1 = 524288;
constexpr int WS_WIH0 = 786432;
constexpr int WS_PLANE = 794624;             // elems/plane; 3.03 MB total as bf16
}

__device__ __forceinline__ float sigm_(float x) { return 1.0f / (1.0f + __expf(-x)); }
__device__ __forceinline__ float tanh_(float x) {
  x = fminf(fmaxf(x, -15.f), 15.f);
  float e = __expf(2.f * x);
  return (e - 1.f) / (e + 1.f);
}

// fp32 -> (hi, lo) bf16 split; hi = RNE(w), lo = RNE(w - hi); w - hi exact in fp32
__device__ __forceinline__ void split_(float w, __hip_bfloat16* hi, __hip_bfloat16* lo) {
  __hip_bfloat16 h = __float2bfloat16(w);
  *hi = h;
  *lo = __float2bfloat16(w - __bfloat162float(h));
}

// weight pre-split pass: hi plane then lo plane in d_ws
__global__ __launch_bounds__(256) void cvt_pair(
    const float* __restrict__ Wih0f, const float* __restrict__ Whh0f,
    const float* __restrict__ Wih1f, const float* __restrict__ Whh1f,
    __hip_bfloat16* __restrict__ ws)
{
  int i = blockIdx.x * 256 + threadIdx.x;
  if (i >= WS_PLANE) return;
  float v;
  if (i < WS_WIH1)       v = Whh0f[i];
  else if (i < WS_WHH1)  v = Wih1f[i - WS_WIH1];
  else if (i < WS_WIH0)  v = Whh1f[i - WS_WHH1];
  else                   v = Wih0f[i - WS_WIH0];
  __hip_bfloat16 hi = __float2bfloat16(v);
  ws[i] = hi;
  ws[WS_PLANE + i] = __float2bfloat16(v - __bfloat162float(hi));
}

// load an 8-elem B fragment as hi/lo pair
template<bool USE_WS>
__device__ __forceinline__ void loadB_(const __hip_bfloat16* wshi, const float* wf, int off,
                                       bf16x8* bhi, bf16x8* blo) {
  if (USE_WS) {
    *bhi = *(const bf16x8*)(wshi + off);
    *blo = *(const bf16x8*)(wshi + WS_PLANE + off);
  } else {
    f32x4 a = *(const f32x4*)(wf + off);
    f32x4 b = *(const f32x4*)(wf + off + 4);
#pragma unroll
    for (int j = 0; j < 4; ++j) {
      float w = a[j]; __bf16 h = (__bf16)w;
      (*bhi)[j] = h; (*blo)[j] = (__bf16)(w - (float)h);
    }
#pragma unroll
    for (int j = 0; j < 4; ++j) {
      float w = b[j]; __bf16 h = (__bf16)w;
      (*bhi)[4 + j] = h; (*blo)[4 + j] = (__bf16)(w - (float)h);
    }
  }
}

// acc += (Ahi+Alo)*(Bhi+Blo), dropping lo*lo (3 MFMAs)
__device__ __forceinline__ f32x4 tri_(bf16x8 ahi, bf16x8 alo, bf16x8 bhi, bf16x8 blo, f32x4 acc) {
  acc = MFMA16(ahi, bhi, acc);
  acc = MFMA16(ahi, blo, acc);
  acc = MFMA16(alo, bhi, acc);
  return acc;
}

template<bool USE_WS>
__global__ __launch_bounds__(512, 2) void lstm_fused(
    const int* __restrict__ x,
    const float* __restrict__ h0,
    const float* __restrict__ c0,
    const float* __restrict__ emb,
    const __hip_bfloat16* __restrict__ wsW,
    const float* __restrict__ Wih0f,
    const float* __restrict__ Whh0f,
    const float* __restrict__ Wih1f,
    const float* __restrict__ Whh1f,
    const float* __restrict__ fcW,
    const float* __restrict__ fcb,
    float* __restrict__ out)             // fp32 output buffer (reference dtype)
{
  __shared__ __align__(16) __hip_bfloat16 h1s[2][2][ROWS][HP_];  // [buf][hi/lo][row][col]
  __shared__ __align__(16) __hip_bfloat16 h2s[2][ROWS][HP_];     // [hi/lo][row][col]
  __shared__ __align__(16) __hip_bfloat16 embs[2][V_][8];
  __shared__ __align__(16) __hip_bfloat16 es[2][ROWS][8];

  const int tid  = threadIdx.x;
  const int lane = tid & 63;
  const int wv   = tid >> 6;
  const int m    = lane & 15;
  const int quad = lane >> 4;
  const int jw   = wv * 32;
  const int r0   = blockIdx.x * ROWS;

  // ---------------- init ----------------
  if (tid < V_) {
#pragma unroll
    for (int j = 0; j < 8; ++j)
      split_(emb[tid * 8 + j], &embs[0][tid][j], &embs[1][tid][j]);
  }
  for (int i = tid; i < ROWS * H_; i += 512) {
    int r = i >> 8, cc = i & 255;
    split_(h0[(0 * B_ + r0 + r) * H_ + cc], &h1s[1][0][r][cc], &h1s[1][1][r][cc]);
    split_(h0[(1 * B_ + r0 + r) * H_ + cc], &h2s[0][r][cc],    &h2s[1][r][cc]);
  }
  f32x4 c1[2][2], c2[2][2];
#pragma unroll
  for (int mt = 0; mt < 2; ++mt)
#pragma unroll
    for (int ct = 0; ct < 2; ++ct)
#pragma unroll
      for (int r = 0; r < 4; ++r) {
        int row = r0 + mt * 16 + quad * 4 + r;
        int col = jw + ct * 16 + m;
        c1[mt][ct][r] = c0[(0 * B_ + row) * H_ + col];
        c2[mt][ct][r] = c0[(1 * B_ + row) * H_ + col];
      }

  bf16x8 zb;
#pragma unroll
  for (int j = 0; j < 8; ++j) zb[j] = (__bf16)0.0f;
  const f32x4 zf = {0.f, 0.f, 0.f, 0.f};

  __syncthreads();

  // ---------------- time loop ----------------
  for (int t = 0; t < T_; ++t) {
    const int p = t & 1, q = p ^ 1;

    if (tid < ROWS) {
      int tok = x[(r0 + tid) * T_ + t];
      tok = tok < 0 ? 0 : (tok >= V_ ? V_ - 1 : tok);
      *(bf16x8*)&es[0][tid][0] = *(const bf16x8*)&embs[0][tok][0];
      *(bf16x8*)&es[1][tid][0] = *(const bf16x8*)&embs[1][tok][0];
    }
    __syncthreads();  // B1

    // ===== layer 0: gates = e @ Wih0^T (K=8 padded to 32) + h1 @ Whh0^T =====
    f32x4 acc[2][8];
    {
      bf16x8 eh0 = zb, el0 = zb, eh1 = zb, el1 = zb;
      if (quad == 0) {
        eh0 = *(const bf16x8*)&es[0][m][0];      el0 = *(const bf16x8*)&es[1][m][0];
        eh1 = *(const bf16x8*)&es[0][16 + m][0]; el1 = *(const bf16x8*)&es[1][16 + m][0];
      }
#pragma unroll
      for (int g = 0; g < 4; ++g)
#pragma unroll
        for (int ct = 0; ct < 2; ++ct) {
          bf16x8 Bh = zb, Bl = zb;
          if (quad == 0) {
            const int off = (g * 256 + jw + ct * 16 + m) * 8;
            loadB_<USE_WS>(wsW + WS_WIH0, Wih0f, off, &Bh, &Bl);
          }
          acc[0][g * 2 + ct] = tri_(eh0, el0, Bh, Bl, zf);
          acc[1][g * 2 + ct] = tri_(eh1, el1, Bh, Bl, zf);
        }
    }
#pragma unroll
    for (int k = 0; k < 8; ++k) {
      const int ko = k * 32 + quad * 8;
      bf16x8 Ah0 = *(const bf16x8*)&h1s[q][0][m][ko];
      bf16x8 Al0 = *(const bf16x8*)&h1s[q][1][m][ko];
      bf16x8 Ah1 = *(const bf16x8*)&h1s[q][0][16 + m][ko];
      bf16x8 Al1 = *(const bf16x8*)&h1s[q][1][16 + m][ko];
#pragma unroll
      for (int g = 0; g < 4; ++g)
#pragma unroll
        for (int ct = 0; ct < 2; ++ct) {
          bf16x8 Bh, Bl;
          const int off = (g * 256 + jw + ct * 16 + m) * H_ + ko;
          loadB_<USE_WS>(wsW + WS_WHH0, Whh0f, off, &Bh, &Bl);
          acc[0][g * 2 + ct] = tri_(Ah0, Al0, Bh, Bl, acc[0][g * 2 + ct]);
          acc[1][g * 2 + ct] = tri_(Ah1, Al1, Bh, Bl, acc[1][g * 2 + ct]);
        }
    }
#pragma unroll
    for (int mt = 0; mt < 2; ++mt)
#pragma unroll
      for (int ct = 0; ct < 2; ++ct)
#pragma unroll
        for (int r = 0; r < 4; ++r) {
          float ig = sigm_(acc[mt][0 + ct][r]);
          float fg = sigm_(acc[mt][2 + ct][r]);
          float gg = tanh_(acc[mt][4 + ct][r]);
          float og = sigm_(acc[mt][6 + ct][r]);
          float cn = fg * c1[mt][ct][r] + ig * gg;
          c1[mt][ct][r] = cn;
          float hv = og * tanh_(cn);
          int rr = mt * 16 + quad * 4 + r, col = jw + ct * 16 + m;
          split_(hv, &h1s[p][0][rr][col], &h1s[p][1][rr][col]);
        }
    __syncthreads();  // B2

    // ===== layer 1: gates = h1_t @ Wih1^T + h2_prev @ Whh1^T =====
#pragma unroll
    for (int mt = 0; mt < 2; ++mt)
#pragma unroll
      for (int nt = 0; nt < 8; ++nt) acc[mt][nt] = zf;
#pragma unroll
    for (int k = 0; k < 8; ++k) {
      const int ko = k * 32 + quad * 8;
      bf16x8 Ah0 = *(const bf16x8*)&h1s[p][0][m][ko];
      bf16x8 Al0 = *(const bf16x8*)&h1s[p][1][m][ko];
      bf16x8 Ah1 = *(const bf16x8*)&h1s[p][0][16 + m][ko];
      bf16x8 Al1 = *(const bf16x8*)&h1s[p][1][16 + m][ko];
      bf16x8 Ch0 = *(const bf16x8*)&h2s[0][m][ko];
      bf16x8 Cl0 = *(const bf16x8*)&h2s[1][m][ko];
      bf16x8 Ch1 = *(const bf16x8*)&h2s[0][16 + m][ko];
      bf16x8 Cl1 = *(const bf16x8*)&h2s[1][16 + m][ko];
#pragma unroll
      for (int g = 0; g < 4; ++g)
#pragma unroll
        for (int ct = 0; ct < 2; ++ct) {
          const int off = (g * 256 + jw + ct * 16 + m) * H_ + ko;
          bf16x8 Bh, Bl;
          loadB_<USE_WS>(wsW + WS_WIH1, Wih1f, off, &Bh, &Bl);
          acc[0][g * 2 + ct] = tri_(Ah0, Al0, Bh, Bl, acc[0][g * 2 + ct]);
          acc[1][g * 2 + ct] = tri_(Ah1, Al1, Bh, Bl, acc[1][g * 2 + ct]);
          loadB_<USE_WS>(wsW + WS_WHH1, Whh1f, off, &Bh, &Bl);
          acc[0][g * 2 + ct] = tri_(Ch0, Cl0, Bh, Bl, acc[0][g * 2 + ct]);
          acc[1][g * 2 + ct] = tri_(Ch1, Cl1, Bh, Bl, acc[1][g * 2 + ct]);
        }
    }
    __syncthreads();  // Bend: h2s reads done before overwrite

#pragma unroll
    for (int mt = 0; mt < 2; ++mt)
#pragma unroll
      for (int ct = 0; ct < 2; ++ct)
#pragma unroll
        for (int r = 0; r < 4; ++r) {
          float ig = sigm_(acc[mt][0 + ct][r]);
          float fg = sigm_(acc[mt][2 + ct][r]);
          float gg = tanh_(acc[mt][4 + ct][r]);
          float og = sigm_(acc[mt][6 + ct][r]);
          float cn = fg * c2[mt][ct][r] + ig * gg;
          c2[mt][ct][r] = cn;
          float hv = og * tanh_(cn);
          int rr = mt * 16 + quad * 4 + r, col = jw + ct * 16 + m;
          split_(hv, &h2s[0][rr][col], &h2s[1][rr][col]);
        }
  }
  __syncthreads();

  // ---------------- outputs (fp32) ----------------
  const int pf = (T_ - 1) & 1;  // == 1

  // h_n = [h1_T, h2_T], fp32 = hi + lo
  for (int i = tid; i < ROWS * H_; i += 512) {
    int r = i >> 8, cc = i & 255;
    out[OUT_HN + (0 * B_ + r0 + r) * H_ + cc] =
        __bfloat162float(h1s[pf][0][r][cc]) + __bfloat162float(h1s[pf][1][r][cc]);
    out[OUT_HN + (1 * B_ + r0 + r) * H_ + cc] =
        __bfloat162float(h2s[0][r][cc]) + __bfloat162float(h2s[1][r][cc]);
  }
  // c_n from fp32 registers
#pragma unroll
  for (int mt = 0; mt < 2; ++mt)
#pragma unroll
    for (int ct = 0; ct < 2; ++ct)
#pragma unroll
      for (int r = 0; r < 4; ++r) {
        int row = r0 + mt * 16 + quad * 4 + r;
        int col = jw + ct * 16 + m;
        out[OUT_CN + row * H_ + col]           = c1[mt][ct][r];
        out[OUT_CN + B_ * H_ + row * H_ + col] = c2[mt][ct][r];
      }
  // logits = h2_T @ fcW^T + fcb, fp32
  for (int i = tid; i < ROWS * V_; i += 512) {
    int r = i / V_, v = i - r * V_;
    const float* wp = fcW + v * H_;
    float s = fcb[v];
#pragma unroll 8
    for (int k = 0; k < H_; ++k) {
      float hk = __bfloat162float(h2s[0][r][k]) + __bfloat162float(h2s[1][r][k]);
      s += hk * wp[k];
    }
    out[(r0 + r) * V_ + v] = s;
  }
}

extern "C" void kernel_launch(void* const* d_in, const int* in_sizes, int n_in,
                              void* d_out, int out_size, void* d_ws, size_t ws_size,
                              hipStream_t stream) {
  (void)in_sizes; (void)n_in; (void)out_size;
  const int*   x    = (const int*)d_in[0];
  const float* h0   = (const float*)d_in[1];
  const float* c0   = (const float*)d_in[2];
  const float* emb  = (const float*)d_in[3];
  const float* Wih0 = (const float*)d_in[4];
  const float* Whh0 = (const float*)d_in[5];
  const float* Wih1 = (const float*)d_in[6];
  const float* Whh1 = (const float*)d_in[7];
  const float* fcW  = (const float*)d_in[8];
  const float* fcb  = (const float*)d_in[9];

  __hip_bfloat16* wsW = (__hip_bfloat16*)d_ws;
  const bool use_ws = (ws_size >= (size_t)(2 * WS_PLANE) * sizeof(__hip_bfloat16));

  if (use_ws) {
    cvt_pair<<<(WS_PLANE + 255) / 256, 256, 0, stream>>>(Wih0, Whh0, Wih1, Whh1, wsW);
    lstm_fused<true><<<B_ / ROWS, 512, 0, stream>>>(
        x, h0, c0, emb, wsW, Wih0, Whh0, Wih1, Whh1, fcW, fcb, (float*)d_out);
  } else {
    lstm_fused<false><<<B_ / ROWS, 512, 0, stream>>>(
        x, h0, c0, emb, wsW, Wih0, Whh0, Wih1, Whh1, fcW, fcb, (float*)d_out);
  }
}